// Round 1
// baseline (345.278 us; speedup 1.0000x reference)
//
#include <hip/hip_runtime.h>
#include <math.h>

#define N_TOT 8192
#define D 128
#define JSPLIT 8
#define TILE 64
#define LDSTRIDE 132   // 128 + 4: keeps float4 alignment (132%4==0), breaks bank aliasing

// ---------------- normalize: hn[i] = h[i] / max(||h[i]||, 1e-12) ----------------
__global__ __launch_bounds__(64) void normalize_kernel(const float* __restrict__ h,
                                                       float* __restrict__ hn) {
    int row = blockIdx.x;
    int lane = threadIdx.x;                    // 64 threads = 1 wave
    const float* hr = h + (size_t)row * D;
    float x0 = hr[lane];
    float x1 = hr[lane + 64];
    float ss = x0 * x0 + x1 * x1;
#pragma unroll
    for (int m = 1; m < 64; m <<= 1) ss += __shfl_xor(ss, m, 64);
    float sc = 1.0f / fmaxf(sqrtf(ss), 1e-12f);
    float* hw = hn + (size_t)row * D;
    hw[lane] = x0 * sc;
    hw[lane + 64] = x1 * sc;
}

// ---------------- pack pos -> (x,y,z, x^2+y^2+z^2) ----------------
__global__ __launch_bounds__(256) void pos4_kernel(const float* __restrict__ pos,
                                                   float4* __restrict__ p4) {
    int t = blockIdx.x * blockDim.x + threadIdx.x;
    if (t < N_TOT) {
        float x = pos[3 * t], y = pos[3 * t + 1], z = pos[3 * t + 2];
        p4[t] = make_float4(x, y, z, x * x + y * y + z * z);
    }
}

// ---------------- fused sim + softmax-partials + positive mask ----------------
// Block: 64 anchors x (N/JSPLIT) j's. Thread (ty,tx) owns rows {ty+16r}, cols {tx+16c}.
__global__ __launch_bounds__(256) void main_kernel(const float* __restrict__ hn,
                                                   const float4* __restrict__ p4,
                                                   float* __restrict__ Ep,
                                                   float* __restrict__ Sp,
                                                   float* __restrict__ Cp) {
    __shared__ float As[TILE * LDSTRIDE];
    __shared__ float Bs[TILE * LDSTRIDE];
    const int tid = threadIdx.x;
    const int tx = tid & 15, ty = tid >> 4;
    const int iblock = blockIdx.x * TILE;
    const int jstart = blockIdx.y * (N_TOT / JSPLIT);

    // stage A tile (64 x 128 floats), coalesced float4
    {
        const float4* g = reinterpret_cast<const float4*>(hn) + (size_t)iblock * (D / 4);
#pragma unroll
        for (int t = 0; t < 8; ++t) {
            int L = tid + 256 * t;
            int r = L >> 5, c4 = L & 31;
            float4 v = g[r * (D / 4) + c4];
            *reinterpret_cast<float4*>(&As[r * LDSTRIDE + c4 * 4]) = v;
        }
    }

    float E[4] = {0, 0, 0, 0}, S[4] = {0, 0, 0, 0}, Cc[4] = {0, 0, 0, 0};
    float4 pi[4];
#pragma unroll
    for (int r = 0; r < 4; ++r) pi[r] = p4[iblock + ty + 16 * r];

    for (int tile = 0; tile < (N_TOT / JSPLIT) / TILE; ++tile) {
        const int jbase = jstart + tile * TILE;
        __syncthreads();
        {
            const float4* g = reinterpret_cast<const float4*>(hn) + (size_t)jbase * (D / 4);
#pragma unroll
            for (int t = 0; t < 8; ++t) {
                int L = tid + 256 * t;
                int r = L >> 5, c4 = L & 31;
                float4 v = g[r * (D / 4) + c4];
                *reinterpret_cast<float4*>(&Bs[r * LDSTRIDE + c4 * 4]) = v;
            }
        }
        __syncthreads();

        float acc[4][4];
#pragma unroll
        for (int r = 0; r < 4; ++r)
#pragma unroll
            for (int c = 0; c < 4; ++c) acc[r][c] = 0.f;

#pragma unroll 2
        for (int k = 0; k < D; k += 4) {
            float4 a[4], b[4];
#pragma unroll
            for (int r = 0; r < 4; ++r)
                a[r] = *reinterpret_cast<const float4*>(&As[(ty + 16 * r) * LDSTRIDE + k]);
#pragma unroll
            for (int c = 0; c < 4; ++c)
                b[c] = *reinterpret_cast<const float4*>(&Bs[(tx + 16 * c) * LDSTRIDE + k]);
#pragma unroll
            for (int r = 0; r < 4; ++r)
#pragma unroll
                for (int c = 0; c < 4; ++c) {
                    acc[r][c] = fmaf(a[r].x, b[c].x, acc[r][c]);
                    acc[r][c] = fmaf(a[r].y, b[c].y, acc[r][c]);
                    acc[r][c] = fmaf(a[r].z, b[c].z, acc[r][c]);
                    acc[r][c] = fmaf(a[r].w, b[c].w, acc[r][c]);
                }
        }

        // epilogue: exp for lse, distance mask for positives
#pragma unroll
        for (int c = 0; c < 4; ++c) {
            int j = jbase + tx + 16 * c;
            float4 pj = p4[j];
#pragma unroll
            for (int r = 0; r < 4; ++r) {
                int i = iblock + ty + 16 * r;
                float t10 = acc[r][c] * 10.0f;         // sim / TAU
                float e = __expf(t10 - 10.0f);         // fixed shift: logits <= 10
                bool self = (i == j);
                E[r] += self ? 0.0f : e;
                float dot = pi[r].x * pj.x + pi[r].y * pj.y + pi[r].z * pj.z;
                float d2 = fmaxf(pi[r].w + pj.w - 2.0f * dot, 0.0f);
                bool isp = (d2 < 0.25f) && !self;      // dist < 0.5
                S[r] += isp ? t10 : 0.0f;
                Cc[r] += isp ? 1.0f : 0.0f;
            }
        }
    }

    // reduce across the 16 lanes sharing ty (lane = (ty%4)*16 + tx inside each wave)
#pragma unroll
    for (int r = 0; r < 4; ++r) {
#pragma unroll
        for (int m = 1; m < 16; m <<= 1) {
            E[r] += __shfl_xor(E[r], m, 64);
            S[r] += __shfl_xor(S[r], m, 64);
            Cc[r] += __shfl_xor(Cc[r], m, 64);
        }
    }
    if (tx == 0) {
#pragma unroll
        for (int r = 0; r < 4; ++r) {
            int i = iblock + ty + 16 * r;
            size_t idx = (size_t)blockIdx.y * N_TOT + i;
            Ep[idx] = E[r];
            Sp[idx] = S[r];
            Cp[idx] = Cc[r];
        }
    }
}

// ---------------- finalize: per-anchor loss + mean over valid ----------------
__global__ __launch_bounds__(1024) void finalize_kernel(const float* __restrict__ Ep,
                                                        const float* __restrict__ Sp,
                                                        const float* __restrict__ Cp,
                                                        float* __restrict__ out) {
    __shared__ float sL[1024];
    __shared__ float sV[1024];
    int tid = threadIdx.x;
    float sumL = 0.f, sumV = 0.f;
    for (int a = tid; a < N_TOT; a += 1024) {
        float E = 0.f, S = 0.f, C = 0.f;
#pragma unroll
        for (int s = 0; s < JSPLIT; ++s) {
            E += Ep[(size_t)s * N_TOT + a];
            S += Sp[(size_t)s * N_TOT + a];
            C += Cp[(size_t)s * N_TOT + a];
        }
        if (C > 0.f) {
            float lse = 10.0f + logf(E);
            sumL += -(S - C * lse) / C;
            sumV += 1.0f;
        }
    }
    sL[tid] = sumL;
    sV[tid] = sumV;
    __syncthreads();
    for (int s = 512; s > 0; s >>= 1) {
        if (tid < s) {
            sL[tid] += sL[tid + s];
            sV[tid] += sV[tid + s];
        }
        __syncthreads();
    }
    if (tid == 0) out[0] = sL[0] / fmaxf(sV[0], 1.0f);
}

extern "C" void kernel_launch(void* const* d_in, const int* in_sizes, int n_in,
                              void* d_out, int out_size, void* d_ws, size_t ws_size,
                              hipStream_t stream) {
    const float* h = (const float*)d_in[0];     // [8,1024,128] fp32
    const float* pos = (const float*)d_in[1];   // [8,1024,3] fp32
    float* out = (float*)d_out;                 // scalar fp32

    char* ws = (char*)d_ws;
    float* hn = (float*)ws;                                       // 8192*128*4 = 4 MB
    float4* p4 = (float4*)(ws + (size_t)N_TOT * D * 4);           // 128 KB
    char* p = ws + (size_t)N_TOT * D * 4 + (size_t)N_TOT * 16;
    float* Ep = (float*)p; p += (size_t)JSPLIT * N_TOT * 4;       // 256 KB
    float* Sp = (float*)p; p += (size_t)JSPLIT * N_TOT * 4;       // 256 KB
    float* Cp = (float*)p;                                        // 256 KB

    normalize_kernel<<<N_TOT, 64, 0, stream>>>(h, hn);
    pos4_kernel<<<N_TOT / 256, 256, 0, stream>>>(pos, p4);
    main_kernel<<<dim3(N_TOT / TILE, JSPLIT), 256, 0, stream>>>(hn, p4, Ep, Sp, Cp);
    finalize_kernel<<<1, 1024, 0, stream>>>(Ep, Sp, Cp, out);
}

// Round 2
// 132.338 us; speedup vs baseline: 2.6091x; 2.6091x over previous
//
#include <hip/hip_runtime.h>
#include <math.h>

#define N_TOT 8192
#define D 128
#define JSPLIT 8

typedef unsigned short ushortT;
typedef __attribute__((ext_vector_type(8))) short short8;
typedef __attribute__((ext_vector_type(4))) float f32x4;

// ---------------- normalize + cast to bf16 ----------------
__device__ __forceinline__ ushortT f2bf(float f) {
    unsigned u = __float_as_uint(f);
    unsigned r = (u + 0x7FFF + ((u >> 16) & 1)) >> 16;   // RNE
    return (ushortT)r;
}

__global__ __launch_bounds__(64) void normalize_kernel(const float* __restrict__ h,
                                                       unsigned* __restrict__ hn2) {
    int row = blockIdx.x;
    int lane = threadIdx.x;
    float2 x = reinterpret_cast<const float2*>(h + (size_t)row * D)[lane];
    float ss = x.x * x.x + x.y * x.y;
#pragma unroll
    for (int m = 1; m < 64; m <<= 1) ss += __shfl_xor(ss, m, 64);
    float sc = 1.0f / fmaxf(sqrtf(ss), 1e-12f);
    unsigned lo = f2bf(x.x * sc), hi = f2bf(x.y * sc);
    hn2[(size_t)row * 64 + lane] = lo | (hi << 16);
}

// ---------------- pack pos -> (x,y,z, x^2+y^2+z^2) ----------------
__global__ __launch_bounds__(256) void pos4_kernel(const float* __restrict__ pos,
                                                   float4* __restrict__ p4) {
    int t = blockIdx.x * blockDim.x + threadIdx.x;
    if (t < N_TOT) {
        float x = pos[3 * t], y = pos[3 * t + 1], z = pos[3 * t + 2];
        p4[t] = make_float4(x, y, z, x * x + y * y + z * z);
    }
}

// ---------------- stage a 128x128 bf16 tile via global_load_lds (width=16) ----------------
__device__ __forceinline__ void stage128(const ushortT* __restrict__ src, ushortT* dst,
                                         int wave, int lane) {
#pragma unroll
    for (int it = 0; it < 8; ++it) {
        int c = it * 4 + wave;                                  // 1 KB chunk index
        const ushortT* g = src + (size_t)(c * 4 + (lane >> 4)) * D + (lane & 15) * 8;
        __builtin_amdgcn_global_load_lds(
            (const __attribute__((address_space(1))) unsigned int*)g,
            (__attribute__((address_space(3))) unsigned int*)(dst + c * 512),
            16, 0, 0);
    }
}

// ---------------- fused MFMA sim + softmax partials + positive mask ----------------
__global__ __launch_bounds__(256, 2) void main_kernel(const ushortT* __restrict__ hn,
                                                      const float4* __restrict__ p4,
                                                      float* __restrict__ Ep,
                                                      float* __restrict__ Sp,
                                                      float* __restrict__ Cp) {
    __shared__ ushortT As[128 * D];
    __shared__ ushortT Bs[128 * D];
    const int tid = threadIdx.x;
    const int wave = tid >> 6, lane = tid & 63;
    const int quad = lane >> 4, l15 = lane & 15;
    const int iblock = blockIdx.x * 128;
    const int jstart = blockIdx.y * (N_TOT / JSPLIT);

    stage128(hn + (size_t)iblock * D, As, wave, lane);
    stage128(hn + (size_t)jstart * D, Bs, wave, lane);

    // per-lane anchor data: 8 i-rows, i = iblock + wave*32 + r*16 + quad*4 + v
    float pix[8], piy[8], piz[8], qiw[8];
#pragma unroll
    for (int idx = 0; idx < 8; ++idx) {
        int i = iblock + wave * 32 + (idx >> 2) * 16 + quad * 4 + (idx & 3);
        float4 p = p4[i];
        pix[idx] = p.x; piy[idx] = p.y; piz[idx] = p.z; qiw[idx] = 0.5f * p.w;
    }
    float Ea[8], Sa[8], Ca[8];
#pragma unroll
    for (int idx = 0; idx < 8; ++idx) { Ea[idx] = 0.f; Sa[idx] = 0.f; Ca[idx] = 0.f; }

    __syncthreads();   // drains A + B(0) staging

    // A fragments: constant for the whole block -> hoist into registers (8 frags, 32 VGPRs)
    short8 afr[4][2];
#pragma unroll
    for (int ks = 0; ks < 4; ++ks)
#pragma unroll
        for (int r = 0; r < 2; ++r)
            afr[ks][r] = *reinterpret_cast<const short8*>(
                &As[(wave * 32 + r * 16 + l15) * D + ks * 32 + quad * 8]);

    for (int jt = 0; jt < 8; ++jt) {
        const int jtbase = jstart + jt * 128;
        if (jt) __syncthreads();              // wait for stage of this j-tile

        f32x4 acc[2][8];
#pragma unroll
        for (int r = 0; r < 2; ++r)
#pragma unroll
            for (int c = 0; c < 8; ++c) acc[r][c] = (f32x4){0.f, 0.f, 0.f, 0.f};

#pragma unroll
        for (int ks = 0; ks < 4; ++ks) {
            short8 b[8];
#pragma unroll
            for (int c = 0; c < 8; ++c)
                b[c] = *reinterpret_cast<const short8*>(
                    &Bs[(c * 16 + l15) * D + ks * 32 + quad * 8]);
#pragma unroll
            for (int r = 0; r < 2; ++r)
#pragma unroll
                for (int c = 0; c < 8; ++c)
                    acc[r][c] = __builtin_amdgcn_mfma_f32_16x16x32_bf16(
                        afr[ks][r], b[c], acc[r][c], 0, 0, 0);
        }

        // issue next tile's staging now; its drain is at the next loop-top barrier,
        // so the async loads overlap the epilogue below
        if (jt < 7) {
            __syncthreads();                  // all waves done reading Bs
            stage128(hn + (size_t)(jtbase + 128) * D, Bs, wave, lane);
        }

        // epilogue
        const bool diag = (jtbase == iblock);
#pragma unroll
        for (int c = 0; c < 8; ++c) {
            int j = jtbase + c * 16 + l15;
            float4 pj = p4[j];
            float qjw = 0.5f * pj.w - 0.125f;
#pragma unroll
            for (int r = 0; r < 2; ++r) {
#pragma unroll
                for (int v = 0; v < 4; ++v) {
                    int idx = r * 4 + v;
                    float s = acc[r][c][v];                       // cosine sim (bf16 inputs)
                    bool self = diag && (wave * 32 + r * 16 + quad * 4 + v == c * 16 + l15);
                    float e = __expf(fmaf(s, 10.f, -10.f));       // exp(sim/TAU - 10)
                    Ea[idx] += self ? 0.f : e;
                    float dot = fmaf(pix[idx], pj.x, fmaf(piy[idx], pj.y, piz[idx] * pj.z));
                    bool isp = (dot > qjw + qiw[idx]) && !self;    // d2 < 0.25
                    Sa[idx] += isp ? s : 0.f;
                    Ca[idx] += isp ? 1.f : 0.f;
                }
            }
        }
    }

    // reduce across the 16 lanes (l15) sharing each i-row; quad bits untouched by xor<16
#pragma unroll
    for (int idx = 0; idx < 8; ++idx) {
#pragma unroll
        for (int m = 1; m < 16; m <<= 1) {
            Ea[idx] += __shfl_xor(Ea[idx], m, 64);
            Sa[idx] += __shfl_xor(Sa[idx], m, 64);
            Ca[idx] += __shfl_xor(Ca[idx], m, 64);
        }
    }
    if (l15 == 0) {
#pragma unroll
        for (int idx = 0; idx < 8; ++idx) {
            int i = iblock + wave * 32 + (idx >> 2) * 16 + quad * 4 + (idx & 3);
            size_t o = (size_t)blockIdx.y * N_TOT + i;
            Ep[o] = Ea[idx]; Sp[o] = Sa[idx]; Cp[o] = Ca[idx];
        }
    }
}

// ---------------- finalize: per-anchor loss + mean over valid ----------------
__global__ __launch_bounds__(1024) void finalize_kernel(const float* __restrict__ Ep,
                                                        const float* __restrict__ Sp,
                                                        const float* __restrict__ Cp,
                                                        float* __restrict__ out) {
    __shared__ float sL[1024];
    __shared__ float sV[1024];
    int tid = threadIdx.x;
    float sumL = 0.f, sumV = 0.f;
    for (int a = tid; a < N_TOT; a += 1024) {
        float E = 0.f, S = 0.f, C = 0.f;
#pragma unroll
        for (int s = 0; s < JSPLIT; ++s) {
            E += Ep[(size_t)s * N_TOT + a];
            S += Sp[(size_t)s * N_TOT + a];
            C += Cp[(size_t)s * N_TOT + a];
        }
        if (C > 0.f) {
            float lse = 10.0f + logf(E);
            sumL += -(10.0f * S - C * lse) / C;    // S stored in sim units
            sumV += 1.0f;
        }
    }
    sL[tid] = sumL;
    sV[tid] = sumV;
    __syncthreads();
    for (int s = 512; s > 0; s >>= 1) {
        if (tid < s) {
            sL[tid] += sL[tid + s];
            sV[tid] += sV[tid + s];
        }
        __syncthreads();
    }
    if (tid == 0) out[0] = sL[0] / fmaxf(sV[0], 1.0f);
}

extern "C" void kernel_launch(void* const* d_in, const int* in_sizes, int n_in,
                              void* d_out, int out_size, void* d_ws, size_t ws_size,
                              hipStream_t stream) {
    const float* h = (const float*)d_in[0];     // [8,1024,128] fp32
    const float* pos = (const float*)d_in[1];   // [8,1024,3] fp32
    float* out = (float*)d_out;                 // scalar fp32

    char* ws = (char*)d_ws;
    ushortT* hn = (ushortT*)ws;                                   // 8192*128*2 = 2 MB bf16
    float4* p4 = (float4*)(ws + (size_t)N_TOT * D * 2);           // 128 KB
    char* p = ws + (size_t)N_TOT * D * 2 + (size_t)N_TOT * 16;
    float* Ep = (float*)p; p += (size_t)JSPLIT * N_TOT * 4;       // 256 KB
    float* Sp = (float*)p; p += (size_t)JSPLIT * N_TOT * 4;       // 256 KB
    float* Cp = (float*)p;                                        // 256 KB

    normalize_kernel<<<N_TOT, 64, 0, stream>>>(h, (unsigned*)hn);
    pos4_kernel<<<N_TOT / 256, 256, 0, stream>>>(pos, p4);
    main_kernel<<<dim3(N_TOT / 128, JSPLIT), 256, 0, stream>>>(hn, p4, Ep, Sp, Cp);
    finalize_kernel<<<1, 1024, 0, stream>>>(Ep, Sp, Cp, out);
}